// Round 2
// baseline (5697.902 us; speedup 1.0000x reference)
//
#include <hip/hip_runtime.h>
#include <hip/hip_bf16.h>

#define B_ 64
#define T_ 256
#define D_ 200
#define H_ 300
#define L_ 8
#define M_ 16384      // T_*B_
#define NG 1800       // 6H
#define NZ 1500       // 5H

typedef __attribute__((ext_vector_type(8))) short bf16x8;
typedef __attribute__((ext_vector_type(4))) float f32x4;
typedef __attribute__((ext_vector_type(4))) unsigned u32x4;
typedef unsigned long long ull;

__device__ __forceinline__ unsigned short f2bf(float f) {
  union { float f; unsigned u; } v; v.f = f;
  unsigned r = v.u + 0x7fffu + ((v.u >> 16) & 1u);   // RNE
  return (unsigned short)(r >> 16);
}

__device__ __forceinline__ float sigf(float x) { return 1.f / (1.f + __expf(-x)); }
__device__ __forceinline__ float tanhf_(float x) {
  x = fminf(15.f, fmaxf(-15.f, x));
  float e = __expf(2.f * x);
  return (e - 1.f) / (e + 1.f);
}

// ---- scope-controlled memory helpers ----
// sc0 only : bypass L1, served by the XCD L2 (fast path, same-XCD coherent)
// sc0 sc1  : system scope, served by MALL (slow path; >= the proven agent-scope path)
__device__ __forceinline__ u32x4 ld128_sc0(const ull* p) {
  u32x4 v;
  asm volatile("global_load_dwordx4 %0, %1, off sc0\n\ts_waitcnt vmcnt(0)"
               : "=v"(v) : "v"(p) : "memory");
  return v;
}
__device__ __forceinline__ u32x4 ld128_sys(const ull* p) {
  u32x4 v;
  asm volatile("global_load_dwordx4 %0, %1, off sc0 sc1\n\ts_waitcnt vmcnt(0)"
               : "=v"(v) : "v"(p) : "memory");
  return v;
}
__device__ __forceinline__ void st64_sc0(ull* p, ull v) {
  asm volatile("global_store_dwordx2 %0, %1, off sc0" :: "v"(p), "v"(v) : "memory");
}
__device__ __forceinline__ void st64_sys(ull* p, ull v) {
  asm volatile("global_store_dwordx2 %0, %1, off sc0 sc1" :: "v"(p), "v"(v) : "memory");
}
__device__ __forceinline__ void st32_sys(unsigned* p, unsigned v) {
  asm volatile("global_store_dword %0, %1, off sc0 sc1" :: "v"(p), "v"(v) : "memory");
}
__device__ __forceinline__ unsigned ld32_sys(const unsigned* p) {
  unsigned v;
  asm volatile("global_load_dword %0, %1, off sc0 sc1\n\ts_waitcnt vmcnt(0)"
               : "=v"(v) : "v"(p) : "memory");
  return v;
}

// ---- weight conversion: W_ih0 (200x1800) then W_ih_rest (7x300x1800) -> bf16 ----
__global__ void k_convert_w(const float* __restrict__ W0, const float* __restrict__ Wr,
                            unsigned short* __restrict__ Wb) {
  int i = blockIdx.x * blockDim.x + threadIdx.x;
  const int n0 = D_ * NG;            // 360000
  const int n1 = (L_ - 1) * H_ * NG; // 3780000
  if (i < n0) Wb[i] = f2bf(W0[i]);
  else if (i < n0 + n1) Wb[i] = f2bf(Wr[i - n0]);
}

// ---- inputs [B,T,D] fp32 -> time-major xb [T,B,D] bf16 ----
__global__ void k_transpose_in(const float* __restrict__ inp, unsigned short* __restrict__ xb) {
  int i = blockIdx.x * blockDim.x + threadIdx.x;     // over T_*B_*D_
  if (i >= T_ * B_ * D_) return;
  int d = i % D_;
  int r = i / D_;       // t*B_+b
  int b = r % B_;
  int t = r / B_;
  xb[i] = f2bf(inp[((size_t)b * T_ + t) * D_ + d]);
}

// ---- hidden[7] [T,B,H] -> output [B,T,H] ----
__global__ void k_out(const float* __restrict__ hid7, float* __restrict__ outp) {
  int i = blockIdx.x * blockDim.x + threadIdx.x;     // over B_*T_*H_
  if (i >= B_ * T_ * H_) return;
  int j = i % H_;
  int r = i / H_;
  int t = r % T_;
  int b = r / T_;
  outp[i] = hid7[((size_t)t * B_ + b) * H_ + j];
}

// ---- pi GEMM: C[M,1800] fp32 = A[M,K] bf16 * B[K,1800] bf16 ----
__global__ __launch_bounds__(256) void k_gemm(const unsigned short* __restrict__ A,
                                              const unsigned short* __restrict__ Bw,
                                              float* __restrict__ C, int K) {
  __shared__ unsigned short As[64 * 40];
  __shared__ unsigned short Bs[64 * 40];
  int bm = blockIdx.x, bn = blockIdx.y;
  int tid = threadIdx.x;
  int lane = tid & 63, wid = tid >> 6;
  int wm = wid & 1, wn = wid >> 1;
  int l16 = lane & 15, quad = lane >> 4;
  f32x4 acc00 = {0,0,0,0}, acc01 = {0,0,0,0}, acc10 = {0,0,0,0}, acc11 = {0,0,0,0};
  int nk = (K + 31) >> 5;
  for (int kc = 0; kc < nk; kc++) {
    int k0 = kc << 5;
    #pragma unroll
    for (int c0 = 0; c0 < 2; c0++) {
      int c = tid + c0 * 256;
      int m = c >> 3, kq = (c & 7) << 2;
      int kk = k0 + kq;
      uint2 val = make_uint2(0u, 0u);
      if (kk < K) val = *(const uint2*)(A + (size_t)(bm * 64 + m) * K + kk);
      *(uint2*)(&As[m * 40 + kq]) = val;
    }
    #pragma unroll
    for (int c0 = 0; c0 < 2; c0++) {
      int c = tid + c0 * 256;
      int krow = c >> 4, nq = (c & 15) << 2;
      int col = bn * 64 + nq;
      uint2 val = make_uint2(0u, 0u);
      if ((k0 + krow) < K && col < NG)
        val = *(const uint2*)(Bw + (size_t)(k0 + krow) * NG + col);
      const unsigned short* pv = (const unsigned short*)&val;
      Bs[(nq + 0) * 40 + krow] = pv[0];
      Bs[(nq + 1) * 40 + krow] = pv[1];
      Bs[(nq + 2) * 40 + krow] = pv[2];
      Bs[(nq + 3) * 40 + krow] = pv[3];
    }
    __syncthreads();
    bf16x8 a0 = *(const bf16x8*)&As[(wm * 32 + l16) * 40 + quad * 8];
    bf16x8 a1 = *(const bf16x8*)&As[(wm * 32 + 16 + l16) * 40 + quad * 8];
    bf16x8 b0 = *(const bf16x8*)&Bs[(wn * 32 + l16) * 40 + quad * 8];
    bf16x8 b1 = *(const bf16x8*)&Bs[(wn * 32 + 16 + l16) * 40 + quad * 8];
    acc00 = __builtin_amdgcn_mfma_f32_16x16x32_bf16(a0, b0, acc00, 0, 0, 0);
    acc01 = __builtin_amdgcn_mfma_f32_16x16x32_bf16(a0, b1, acc01, 0, 0, 0);
    acc10 = __builtin_amdgcn_mfma_f32_16x16x32_bf16(a1, b0, acc10, 0, 0, 0);
    acc11 = __builtin_amdgcn_mfma_f32_16x16x32_bf16(a1, b1, acc11, 0, 0, 0);
    __syncthreads();
  }
  int rowb = bm * 64 + wm * 32 + quad * 4;
  int colb = bn * 64 + wn * 32 + l16;
  #pragma unroll
  for (int i = 0; i < 4; i++) {
    if (colb < NG) {
      C[(size_t)(rowb + i) * NG + colb] = acc00[i];
      C[(size_t)(rowb + 16 + i) * NG + colb] = acc10[i];
    }
    if (colb + 16 < NG) {
      C[(size_t)(rowb + i) * NG + colb + 16] = acc01[i];
      C[(size_t)(rowb + 16 + i) * NG + colb + 16] = acc11[i];
    }
  }
}

// ---- persistent recurrence: 192 blocks = 16 batch-groups (4 rows) x 12 column-blocks ----
// R6: XCD-local L2 exchange. With round-robin block->XCD dispatch, all 12 blocks
// of a group (bid = g + 16*cb) share one XCD -> sc0 stores/loads are coherent via
// that L2 (~200cy RT) instead of the MALL (~700cy). Safety: step-1 poll is
// BOUNDED; each block publishes a got-vote (system scope, always works); the
// group demotes UNIFORMLY to a separate system-scope area if any block failed.
// Producers==consumers, so a split group fails in every block (no mixed state).
// Placement static within a launch -> unbounded fast polls safe after consensus.
__global__ __launch_bounds__(512, 2) void k_recur(
    const float* __restrict__ pi, const float* __restrict__ Whh,
    const float* __restrict__ bias, const int* __restrict__ lens,
    float* __restrict__ hid, unsigned short* __restrict__ xb,
    ull* __restrict__ h_words, int rev, int tagbase)
{
  __shared__ __align__(16) unsigned short h_lds[16 * 328]; // bf16 [row][k], rows 4-15 & k>=300 zero
  __shared__ __align__(16) float z_lds[128 * 4];           // [n][r]
  __shared__ float bias_s[128];
  __shared__ int len_s[4];
  __shared__ int mode_s;     // 1 = fast (L2/sc0), 0 = slow (MALL/system)
  __shared__ int cons_s;

  const int tid = threadIdx.x;
  const int bid = blockIdx.x;
  const int g = bid & 15;    // batch group
  const int cb = bid >> 4;   // column block 0..11

  const int lane = tid & 63;
  const int wid = tid >> 6;          // 0..7 = N-tile index
  const int l16 = lane & 15;
  const int quad = lane >> 4;

  const int rp = tid / 25;           // gate mapping (tid<50): row-pair 0..1
  const int gj = tid - rp * 25;      // j within 25
  const int j2 = cb * 25 + gj;

  // ---- preload Whh B-fragments: wfrag[c], n = wid*16+l16, k = c*32+quad*8+j ----
  bf16x8 wfrag[10];
  {
    int n = wid * 16 + l16;
    bool vn = n < 125;
    int colw = vn ? ((n / 25) * 300 + cb * 25 + (n % 25)) : 0;
    #pragma unroll
    for (int c = 0; c < 10; c++) {
      bf16x8 f;
      #pragma unroll
      for (int j = 0; j < 8; j++) {
        int k = c * 32 + quad * 8 + j;
        float v = (vn && k < 300) ? Whh[(size_t)k * NZ + colw] : 0.f;
        f[j] = (short)f2bf(v);
      }
      wfrag[c] = f;
    }
  }
  if (tid < 4) len_s[tid] = lens[g * 4 + tid];
  if (tid < 125) bias_s[tid] = bias[(tid / 25) * 300 + cb * 25 + (tid % 25)];
  if (tid == 0) { mode_s = 1; cons_s = 1; }
  for (int i = tid; i < 16 * 328; i += 512) h_lds[i] = 0;  // zero pad rows/cols
  __syncthreads();

  int S = len_s[0];
  S = len_s[1] > S ? len_s[1] : S;
  S = len_s[2] > S ? len_s[2] : S;
  S = len_s[3] > S ? len_s[3] : S;

  ull* hwf = h_words + (size_t)g * 1200;                   // fast area [parity][600]
  ull* hws = h_words + 16 * 1200 + (size_t)g * 1200;       // slow area [parity][600]
  unsigned* votes = (unsigned*)(h_words + 32 * 1200) + g * 12;
  const int brbase = g * 4;
  float cA = 0.f, cB = 0.f;          // cell state, rows 2rp / 2rp+1 (tid<50)
  ull lastw = 0;                     // last published word (gate threads)

  for (int s = 0; s < S; s++) {
    // gate threads prefetch their 12 pi values (in flight across the poll)
    float pA0 = 0.f, pA1 = 0.f, pA2 = 0.f, pA3 = 0.f, pA4 = 0.f, pA6 = 0.f;
    float pB0 = 0.f, pB1 = 0.f, pB2 = 0.f, pB3 = 0.f, pB4 = 0.f, pB6 = 0.f;
    if (tid < 50) {
      int lrA = len_s[2 * rp], lrB = len_s[2 * rp + 1];
      if (s < lrA) {
        int t = rev ? (lrA - 1 - s) : s;
        const float* pr = pi + ((size_t)t * B_ + (brbase + 2 * rp)) * NG;
        pA0 = pr[0 * 300 + j2]; pA1 = pr[1 * 300 + j2]; pA2 = pr[2 * 300 + j2];
        pA3 = pr[3 * 300 + j2]; pA4 = pr[4 * 300 + j2]; pA6 = pr[NZ + j2];
      }
      if (s < lrB) {
        int t = rev ? (lrB - 1 - s) : s;
        const float* pr = pi + ((size_t)t * B_ + (brbase + 2 * rp + 1)) * NG;
        pB0 = pr[0 * 300 + j2]; pB1 = pr[1 * 300 + j2]; pB2 = pr[2 * 300 + j2];
        pB3 = pr[3 * 300 + j2]; pB4 = pr[4 * 300 + j2]; pB6 = pr[NZ + j2];
      }
    }

    if (s > 0) {
      const unsigned tg = (unsigned)(tagbase + s);          // tag of h_s
      const size_t par = (size_t)(s & 1) * 600;
      u32x4 v = {0, 0, 0, 0};
      if (s == 1) {
        // ---- bounded fast attempt + group-wide vote ----
        bool got = (tid >= 300);
        if (tid < 300) {
          const ull* pf = hwf + par + 2 * tid;
          for (int it = 0; it < 384 && !got; ++it) {
            v = ld128_sc0(pf);
            got = (v.y == tg) && (v.w == tg);
          }
        }
        int blockgot = __syncthreads_and((int)got);
        if (tid == 0) st32_sys(votes + cb, (tg << 1) | (unsigned)(blockgot & 1));
        __syncthreads();
        if (tid < 12) {
          unsigned vv;
          do { vv = ld32_sys(votes + tid); } while ((vv >> 1) != tg);
          if (!(vv & 1)) cons_s = 0;      // benign LDS race (all write 0)
        }
        __syncthreads();
        if (!cons_s) {
          // uniform demote: republish own words to slow area; fill missing from it
          if (tid == 0) mode_s = 0;
          if (tid < 50) st64_sys(hws + 600 + rp * 300 + j2, lastw);  // tag-1 parity=1
          if (tid < 300 && !got) {
            const ull* ps = hws + par + 2 * tid;
            for (;;) {
              v = ld128_sys(ps);
              if ((v.y == tg) && (v.w == tg)) break;
              __builtin_amdgcn_s_sleep(1);
            }
          }
        }
      } else {
        if (mode_s) {
          if (tid < 300) {
            const ull* pf = hwf + par + 2 * tid;
            for (;;) {
              v = ld128_sc0(pf);
              if ((v.y == tg) && (v.w == tg)) break;
            }
          }
        } else {
          if (tid < 300) {
            const ull* ps = hws + par + 2 * tid;
            for (;;) {
              v = ld128_sys(ps);
              if ((v.y == tg) && (v.w == tg)) break;
              __builtin_amdgcn_s_sleep(1);
            }
          }
        }
      }
      // stash bf16 payloads into LDS A-operand layout (2 rows per u64 word)
      if (tid < 300) {
        int w0 = tid << 1;
        int r2 = (w0 >= 300) ? 1 : 0;
        int k = w0 - r2 * 300;
        h_lds[(2 * r2) * 328 + k]     = (unsigned short)(v.x >> 16);
        h_lds[(2 * r2 + 1) * 328 + k] = (unsigned short)(v.x & 0xffffu);
        int w1 = w0 + 1;
        int r2b = (w1 >= 300) ? 1 : 0;
        int kb = w1 - r2b * 300;
        h_lds[(2 * r2b) * 328 + kb]     = (unsigned short)(v.z >> 16);
        h_lds[(2 * r2b + 1) * 328 + kb] = (unsigned short)(v.z & 0xffffu);
      }
    }
    __syncthreads();

    f32x4 acc = {0, 0, 0, 0};
    if (s > 0) {
      f32x4 acc2 = {0, 0, 0, 0};
      const unsigned short* abase = &h_lds[l16 * 328 + quad * 8];
      #pragma unroll
      for (int c = 0; c < 10; c += 2) {
        bf16x8 a0 = *(const bf16x8*)(abase + c * 32);
        bf16x8 a1 = *(const bf16x8*)(abase + c * 32 + 32);
        acc  = __builtin_amdgcn_mfma_f32_16x16x32_bf16(a0, wfrag[c],     acc,  0, 0, 0);
        acc2 = __builtin_amdgcn_mfma_f32_16x16x32_bf16(a1, wfrag[c + 1], acc2, 0, 0, 0);
      }
      acc += acc2;
    }
    // C layout: col=lane&15, row=quad*4+reg -> lanes 0-15 hold rows 0-3 in regs 0-3
    if (quad == 0) {
      int n = wid * 16 + l16;
      *(f32x4*)&z_lds[n * 4] = acc;
    }
    __syncthreads();

    if (tid < 50) {
      const float bb0 = bias_s[gj],      bb1 = bias_s[25 + gj], bb2 = bias_s[50 + gj];
      const float bb3 = bias_s[75 + gj], bb4 = bias_s[100 + gj];
      const float2 z0 = *(const float2*)&z_lds[(gj      ) * 4 + 2 * rp];
      const float2 z1 = *(const float2*)&z_lds[(25 + gj ) * 4 + 2 * rp];
      const float2 z2 = *(const float2*)&z_lds[(50 + gj ) * 4 + 2 * rp];
      const float2 z3 = *(const float2*)&z_lds[(75 + gj ) * 4 + 2 * rp];
      const float2 z4 = *(const float2*)&z_lds[(100 + gj) * 4 + 2 * rp];
      // row A = 2rp
      float iA = sigf(z0.x + pA0 + bb0);
      float fA = sigf(z1.x + pA1 + bb1);
      float gA = tanhf_(z2.x + pA2 + bb2);
      float oA = sigf(z3.x + pA3 + bb3);
      float rA = sigf(z4.x + pA4 + bb4);
      float cnA = iA * gA + fA * cA; cA = cnA;
      float hA = rA * (oA * tanhf_(cnA)) + (1.f - rA) * pA6;
      // row B = 2rp+1
      float iB = sigf(z0.y + pB0 + bb0);
      float fB = sigf(z1.y + pB1 + bb1);
      float gB = tanhf_(z2.y + pB2 + bb2);
      float oB = sigf(z3.y + pB3 + bb3);
      float rB = sigf(z4.y + pB4 + bb4);
      float cnB = iB * gB + fB * cB; cB = cnB;
      float hB = rB * (oB * tanhf_(cnB)) + (1.f - rB) * pB6;

      unsigned short hbA = f2bf(hA), hbB = f2bf(hB);
      ull word = ((ull)(unsigned)(tagbase + s + 1) << 32)
               | ((unsigned)hbA << 16) | (unsigned)hbB;
      lastw = word;
      int pidx = ((s + 1) & 1) * 600 + rp * 300 + j2;
      if (mode_s) st64_sc0(hwf + pidx, word);
      else        st64_sys(hws + pidx, word);
      int lrA = len_s[2 * rp], lrB = len_s[2 * rp + 1];
      if (s < lrA) {
        int t = rev ? (lrA - 1 - s) : s;
        int br = brbase + 2 * rp;
        hid[((size_t)t * B_ + br) * H_ + j2] = hA;
        xb[((size_t)t * B_ + br) * H_ + j2] = hbA;
      }
      if (s < lrB) {
        int t = rev ? (lrB - 1 - s) : s;
        int br = brbase + 2 * rp + 1;
        hid[((size_t)t * B_ + br) * H_ + j2] = hB;
        xb[((size_t)t * B_ + br) * H_ + j2] = hbB;
      }
    }
    // no trailing barrier needed: next stash can only start after our own gates
    // publish (we poll our own words too); h_lds/z_lds hazards separated by the
    // two barriers above.
  }
}

extern "C" void kernel_launch(void* const* d_in, const int* in_sizes, int n_in,
                              void* d_out, int out_size, void* d_ws, size_t ws_size,
                              hipStream_t stream) {
  const float* inputs = (const float*)d_in[0];
  const int* lengths = (const int*)d_in[1];
  const float* W_ih0 = (const float*)d_in[2];
  const float* W_ih_rest = (const float*)d_in[3];
  const float* W_hh = (const float*)d_in[4];
  const float* b_hh = (const float*)d_in[5];
  float* outp = (float*)d_out;
  float* hidden = outp + (size_t)B_ * T_ * H_;   // [L][T,B,H]

  char* ws = (char*)d_ws;
  float* pi = (float*)ws;                                         // M_*NG fp32 (118MB)
  size_t off = (size_t)M_ * NG * 4;
  unsigned short* xb = (unsigned short*)(ws + off);               // M_*H_ bf16
  off += (size_t)M_ * H_ * 2;
  unsigned short* Wb = (unsigned short*)(ws + off);               // 4,140,000 bf16
  off += 4140000ull * 2;
  ull* h_words = (ull*)(ws + off);   // fast[16][1200] + slow[16][1200] u64 + votes[16][12] u32
  size_t hw_bytes = 32ull * 1200 * 8 + 16ull * 12 * 4;
  off += hw_bytes;

  hipMemsetAsync(d_out, 0, (size_t)out_size * 4, stream);         // zero padding regions
  hipMemsetAsync(h_words, 0, hw_bytes, stream);                   // clear tags + votes

  {
    int n = D_ * NG + (L_ - 1) * H_ * NG;
    k_convert_w<<<(n + 255) / 256, 256, 0, stream>>>(W_ih0, W_ih_rest, Wb);
  }
  {
    int n = T_ * B_ * D_;
    k_transpose_in<<<(n + 255) / 256, 256, 0, stream>>>(inputs, xb);
  }
  for (int l = 0; l < L_; l++) {
    const unsigned short* Wihb = (l == 0) ? Wb : (Wb + 360000 + (size_t)(l - 1) * 540000);
    int K = (l == 0) ? D_ : H_;
    k_gemm<<<dim3(M_ / 64, (NG + 63) / 64), 256, 0, stream>>>(xb, Wihb, pi, K);
    float* hid_l = hidden + (size_t)l * T_ * B_ * H_;
    k_recur<<<192, 512, 0, stream>>>(pi, W_hh + (size_t)l * H_ * NZ, b_hh + (size_t)l * NZ,
                                     lengths, hid_l, xb, h_words, l & 1, l * 300);
  }
  k_out<<<((B_ * T_ * H_) + 255) / 256, 256, 0, stream>>>(
      hidden + (size_t)(L_ - 1) * T_ * B_ * H_, outp);
}

// Round 3
// 4137.702 us; speedup vs baseline: 1.3771x; 1.3771x over previous
//
#include <hip/hip_runtime.h>
#include <hip/hip_bf16.h>

#define B_ 64
#define T_ 256
#define D_ 200
#define H_ 300
#define L_ 8
#define M_ 16384      // T_*B_
#define NG 1800       // 6H
#define NZ 1500       // 5H

typedef __attribute__((ext_vector_type(8))) short bf16x8;
typedef __attribute__((ext_vector_type(4))) float f32x4;
typedef __attribute__((ext_vector_type(4))) unsigned u32x4;
typedef unsigned long long ull;

__device__ __forceinline__ unsigned short f2bf(float f) {
  union { float f; unsigned u; } v; v.f = f;
  unsigned r = v.u + 0x7fffu + ((v.u >> 16) & 1u);   // RNE
  return (unsigned short)(r >> 16);
}

__device__ __forceinline__ float sigf(float x) { return 1.f / (1.f + __expf(-x)); }
__device__ __forceinline__ float tanhf_(float x) {
  x = fminf(15.f, fmaxf(-15.f, x));
  float e = __expf(2.f * x);
  return (e - 1.f) / (e + 1.f);
}

// ---- exchange memory helpers ----
// fast path: plain store -> producer XCD's write-back L2; nt load -> no-allocate
//            (bypasses L1 retention), served by the local L2 (~120cy) when
//            producer and consumer share an XCD.
// slow path: sc0 sc1 (system scope) -> MALL, always correct, ~700cy.
__device__ __forceinline__ u32x4 ld128_nt(const ull* p) {
  u32x4 v;
  asm volatile("global_load_dwordx4 %0, %1, off nt\n\ts_waitcnt vmcnt(0)"
               : "=v"(v) : "v"(p) : "memory");
  return v;
}
__device__ __forceinline__ u32x4 ld128_sys(const ull* p) {
  u32x4 v;
  asm volatile("global_load_dwordx4 %0, %1, off sc0 sc1\n\ts_waitcnt vmcnt(0)"
               : "=v"(v) : "v"(p) : "memory");
  return v;
}
__device__ __forceinline__ void st64_plain(ull* p, ull v) {
  asm volatile("global_store_dwordx2 %0, %1, off" :: "v"(p), "v"(v) : "memory");
}
__device__ __forceinline__ void st64_sys(ull* p, ull v) {
  asm volatile("global_store_dwordx2 %0, %1, off sc0 sc1" :: "v"(p), "v"(v) : "memory");
}

// ---- weight conversion: W_ih0 (200x1800) then W_ih_rest (7x300x1800) -> bf16 ----
__global__ void k_convert_w(const float* __restrict__ W0, const float* __restrict__ Wr,
                            unsigned short* __restrict__ Wb) {
  int i = blockIdx.x * blockDim.x + threadIdx.x;
  const int n0 = D_ * NG;            // 360000
  const int n1 = (L_ - 1) * H_ * NG; // 3780000
  if (i < n0) Wb[i] = f2bf(W0[i]);
  else if (i < n0 + n1) Wb[i] = f2bf(Wr[i - n0]);
}

// ---- inputs [B,T,D] fp32 -> time-major xb [T,B,D] bf16 ----
__global__ void k_transpose_in(const float* __restrict__ inp, unsigned short* __restrict__ xb) {
  int i = blockIdx.x * blockDim.x + threadIdx.x;     // over T_*B_*D_
  if (i >= T_ * B_ * D_) return;
  int d = i % D_;
  int r = i / D_;       // t*B_+b
  int b = r % B_;
  int t = r / B_;
  xb[i] = f2bf(inp[((size_t)b * T_ + t) * D_ + d]);
}

// ---- hidden[7] [T,B,H] -> output [B,T,H] ----
__global__ void k_out(const float* __restrict__ hid7, float* __restrict__ outp) {
  int i = blockIdx.x * blockDim.x + threadIdx.x;     // over B_*T_*H_
  if (i >= B_ * T_ * H_) return;
  int j = i % H_;
  int r = i / H_;
  int t = r % T_;
  int b = r / T_;
  outp[i] = hid7[((size_t)t * B_ + b) * H_ + j];
}

// ---- pi GEMM: C[M,1800] fp32 = A[M,K] bf16 * B[K,1800] bf16 ----
__global__ __launch_bounds__(256) void k_gemm(const unsigned short* __restrict__ A,
                                              const unsigned short* __restrict__ Bw,
                                              float* __restrict__ C, int K) {
  __shared__ unsigned short As[64 * 40];
  __shared__ unsigned short Bs[64 * 40];
  int bm = blockIdx.x, bn = blockIdx.y;
  int tid = threadIdx.x;
  int lane = tid & 63, wid = tid >> 6;
  int wm = wid & 1, wn = wid >> 1;
  int l16 = lane & 15, quad = lane >> 4;
  f32x4 acc00 = {0,0,0,0}, acc01 = {0,0,0,0}, acc10 = {0,0,0,0}, acc11 = {0,0,0,0};
  int nk = (K + 31) >> 5;
  for (int kc = 0; kc < nk; kc++) {
    int k0 = kc << 5;
    #pragma unroll
    for (int c0 = 0; c0 < 2; c0++) {
      int c = tid + c0 * 256;
      int m = c >> 3, kq = (c & 7) << 2;
      int kk = k0 + kq;
      uint2 val = make_uint2(0u, 0u);
      if (kk < K) val = *(const uint2*)(A + (size_t)(bm * 64 + m) * K + kk);
      *(uint2*)(&As[m * 40 + kq]) = val;
    }
    #pragma unroll
    for (int c0 = 0; c0 < 2; c0++) {
      int c = tid + c0 * 256;
      int krow = c >> 4, nq = (c & 15) << 2;
      int col = bn * 64 + nq;
      uint2 val = make_uint2(0u, 0u);
      if ((k0 + krow) < K && col < NG)
        val = *(const uint2*)(Bw + (size_t)(k0 + krow) * NG + col);
      const unsigned short* pv = (const unsigned short*)&val;
      Bs[(nq + 0) * 40 + krow] = pv[0];
      Bs[(nq + 1) * 40 + krow] = pv[1];
      Bs[(nq + 2) * 40 + krow] = pv[2];
      Bs[(nq + 3) * 40 + krow] = pv[3];
    }
    __syncthreads();
    bf16x8 a0 = *(const bf16x8*)&As[(wm * 32 + l16) * 40 + quad * 8];
    bf16x8 a1 = *(const bf16x8*)&As[(wm * 32 + 16 + l16) * 40 + quad * 8];
    bf16x8 b0 = *(const bf16x8*)&Bs[(wn * 32 + l16) * 40 + quad * 8];
    bf16x8 b1 = *(const bf16x8*)&Bs[(wn * 32 + 16 + l16) * 40 + quad * 8];
    acc00 = __builtin_amdgcn_mfma_f32_16x16x32_bf16(a0, b0, acc00, 0, 0, 0);
    acc01 = __builtin_amdgcn_mfma_f32_16x16x32_bf16(a0, b1, acc01, 0, 0, 0);
    acc10 = __builtin_amdgcn_mfma_f32_16x16x32_bf16(a1, b0, acc10, 0, 0, 0);
    acc11 = __builtin_amdgcn_mfma_f32_16x16x32_bf16(a1, b1, acc11, 0, 0, 0);
    __syncthreads();
  }
  int rowb = bm * 64 + wm * 32 + quad * 4;
  int colb = bn * 64 + wn * 32 + l16;
  #pragma unroll
  for (int i = 0; i < 4; i++) {
    if (colb < NG) {
      C[(size_t)(rowb + i) * NG + colb] = acc00[i];
      C[(size_t)(rowb + 16 + i) * NG + colb] = acc10[i];
    }
    if (colb + 16 < NG) {
      C[(size_t)(rowb + i) * NG + colb + 16] = acc01[i];
      C[(size_t)(rowb + 16 + i) * NG + colb + 16] = acc11[i];
    }
  }
}

// ---- persistent recurrence: 192 blocks = 16 batch-groups (4 rows) x 12 column-blocks ----
// R7 exchange: dual-publish + self-healing poll.
//  * gates publish each h-word TWICE: plain store (fast area, lands in the
//    producer XCD's L2) and system store (slow area, MALL, always visible).
//  * pollers (waves 1-5, tid 64..363) spin with nt loads on the fast area —
//    nt never allocates in L1, so polls are served by the local L2 (~120cy)
//    when the group's 12 blocks share an XCD (bid = g+16cb -> same bid%8).
//    Every 8th miss they probe the slow area at system scope, which is always
//    correct -> liveness holds even if nt semantics or XCD placement differ.
//  * wave 0 (gate lanes + their outstanding pi-prefetch loads and publish
//    stores) is excluded from polling so its vmcnt backlog never serializes
//    against the poll's vmcnt(0).
__global__ __launch_bounds__(512, 2) void k_recur(
    const float* __restrict__ pi, const float* __restrict__ Whh,
    const float* __restrict__ bias, const int* __restrict__ lens,
    float* __restrict__ hid, unsigned short* __restrict__ xb,
    ull* __restrict__ h_words, int rev, int tagbase)
{
  __shared__ __align__(16) unsigned short h_lds[16 * 328]; // bf16 [row][k], rows 4-15 & k>=300 zero
  __shared__ __align__(16) float z_lds[128 * 4];           // [n][r]
  __shared__ float bias_s[128];
  __shared__ int len_s[4];

  const int tid = threadIdx.x;
  const int bid = blockIdx.x;
  const int g = bid & 15;    // batch group
  const int cb = bid >> 4;   // column block 0..11

  const int lane = tid & 63;
  const int wid = tid >> 6;          // 0..7 = N-tile index
  const int l16 = lane & 15;
  const int quad = lane >> 4;

  const int rp = tid / 25;           // gate mapping (tid<50): row-pair 0..1
  const int gj = tid - rp * 25;      // j within 25
  const int j2 = cb * 25 + gj;

  // ---- preload Whh B-fragments: wfrag[c], n = wid*16+l16, k = c*32+quad*8+j ----
  bf16x8 wfrag[10];
  {
    int n = wid * 16 + l16;
    bool vn = n < 125;
    int colw = vn ? ((n / 25) * 300 + cb * 25 + (n % 25)) : 0;
    #pragma unroll
    for (int c = 0; c < 10; c++) {
      bf16x8 f;
      #pragma unroll
      for (int j = 0; j < 8; j++) {
        int k = c * 32 + quad * 8 + j;
        float v = (vn && k < 300) ? Whh[(size_t)k * NZ + colw] : 0.f;
        f[j] = (short)f2bf(v);
      }
      wfrag[c] = f;
    }
  }
  if (tid < 4) len_s[tid] = lens[g * 4 + tid];
  if (tid < 125) bias_s[tid] = bias[(tid / 25) * 300 + cb * 25 + (tid % 25)];
  for (int i = tid; i < 16 * 328; i += 512) h_lds[i] = 0;  // zero pad rows/cols
  __syncthreads();

  int S = len_s[0];
  S = len_s[1] > S ? len_s[1] : S;
  S = len_s[2] > S ? len_s[2] : S;
  S = len_s[3] > S ? len_s[3] : S;

  ull* hwf = h_words + (size_t)g * 1200;                   // fast area [parity][600]
  ull* hws = h_words + 16 * 1200 + (size_t)g * 1200;       // slow area [parity][600]
  const int brbase = g * 4;
  float cA = 0.f, cB = 0.f;          // cell state, rows 2rp / 2rp+1 (tid<50)

  for (int s = 0; s < S; s++) {
    // gate threads prefetch their 12 pi values (in flight across the poll)
    float pA0 = 0.f, pA1 = 0.f, pA2 = 0.f, pA3 = 0.f, pA4 = 0.f, pA6 = 0.f;
    float pB0 = 0.f, pB1 = 0.f, pB2 = 0.f, pB3 = 0.f, pB4 = 0.f, pB6 = 0.f;
    if (tid < 50) {
      int lrA = len_s[2 * rp], lrB = len_s[2 * rp + 1];
      if (s < lrA) {
        int t = rev ? (lrA - 1 - s) : s;
        const float* pr = pi + ((size_t)t * B_ + (brbase + 2 * rp)) * NG;
        pA0 = pr[0 * 300 + j2]; pA1 = pr[1 * 300 + j2]; pA2 = pr[2 * 300 + j2];
        pA3 = pr[3 * 300 + j2]; pA4 = pr[4 * 300 + j2]; pA6 = pr[NZ + j2];
      }
      if (s < lrB) {
        int t = rev ? (lrB - 1 - s) : s;
        const float* pr = pi + ((size_t)t * B_ + (brbase + 2 * rp + 1)) * NG;
        pB0 = pr[0 * 300 + j2]; pB1 = pr[1 * 300 + j2]; pB2 = pr[2 * 300 + j2];
        pB3 = pr[3 * 300 + j2]; pB4 = pr[4 * 300 + j2]; pB6 = pr[NZ + j2];
      }
    }

    if (s > 0 && tid >= 64 && tid < 364) {
      const unsigned tg = (unsigned)(tagbase + s);          // tag of h_s
      const size_t par = (size_t)(s & 1) * 600;
      const int pt = tid - 64;                              // 0..299
      const ull* pf = hwf + par + 2 * pt;
      const ull* ps = hws + par + 2 * pt;
      u32x4 v;
      int miss = 0;
      for (;;) {
        v = ld128_nt(pf);                                   // local-L2 fast probe
        if ((v.y == tg) && (v.w == tg)) break;
        if ((++miss & 7) == 0) {
          v = ld128_sys(ps);                                // MALL truth probe
          if ((v.y == tg) && (v.w == tg)) break;
          __builtin_amdgcn_s_sleep(1);
        }
      }
      // stash bf16 payloads into LDS A-operand layout (2 rows per u64 word)
      int w0 = pt << 1;
      int r2 = (w0 >= 300) ? 1 : 0;
      int k = w0 - r2 * 300;
      h_lds[(2 * r2) * 328 + k]     = (unsigned short)(v.x >> 16);
      h_lds[(2 * r2 + 1) * 328 + k] = (unsigned short)(v.x & 0xffffu);
      int w1 = w0 + 1;
      int r2b = (w1 >= 300) ? 1 : 0;
      int kb = w1 - r2b * 300;
      h_lds[(2 * r2b) * 328 + kb]     = (unsigned short)(v.z >> 16);
      h_lds[(2 * r2b + 1) * 328 + kb] = (unsigned short)(v.z & 0xffffu);
    }
    __syncthreads();

    f32x4 acc = {0, 0, 0, 0};
    if (s > 0) {
      f32x4 acc2 = {0, 0, 0, 0};
      const unsigned short* abase = &h_lds[l16 * 328 + quad * 8];
      #pragma unroll
      for (int c = 0; c < 10; c += 2) {
        bf16x8 a0 = *(const bf16x8*)(abase + c * 32);
        bf16x8 a1 = *(const bf16x8*)(abase + c * 32 + 32);
        acc  = __builtin_amdgcn_mfma_f32_16x16x32_bf16(a0, wfrag[c],     acc,  0, 0, 0);
        acc2 = __builtin_amdgcn_mfma_f32_16x16x32_bf16(a1, wfrag[c + 1], acc2, 0, 0, 0);
      }
      acc += acc2;
    }
    // C layout: col=lane&15, row=quad*4+reg -> lanes 0-15 hold rows 0-3 in regs 0-3
    if (quad == 0) {
      int n = wid * 16 + l16;
      *(f32x4*)&z_lds[n * 4] = acc;
    }
    __syncthreads();

    if (tid < 50) {
      const float bb0 = bias_s[gj],      bb1 = bias_s[25 + gj], bb2 = bias_s[50 + gj];
      const float bb3 = bias_s[75 + gj], bb4 = bias_s[100 + gj];
      const float2 z0 = *(const float2*)&z_lds[(gj      ) * 4 + 2 * rp];
      const float2 z1 = *(const float2*)&z_lds[(25 + gj ) * 4 + 2 * rp];
      const float2 z2 = *(const float2*)&z_lds[(50 + gj ) * 4 + 2 * rp];
      const float2 z3 = *(const float2*)&z_lds[(75 + gj ) * 4 + 2 * rp];
      const float2 z4 = *(const float2*)&z_lds[(100 + gj) * 4 + 2 * rp];
      // row A = 2rp
      float iA = sigf(z0.x + pA0 + bb0);
      float fA = sigf(z1.x + pA1 + bb1);
      float gA = tanhf_(z2.x + pA2 + bb2);
      float oA = sigf(z3.x + pA3 + bb3);
      float rA = sigf(z4.x + pA4 + bb4);
      float cnA = iA * gA + fA * cA; cA = cnA;
      float hA = rA * (oA * tanhf_(cnA)) + (1.f - rA) * pA6;
      // row B = 2rp+1
      float iB = sigf(z0.y + pB0 + bb0);
      float fB = sigf(z1.y + pB1 + bb1);
      float gB = tanhf_(z2.y + pB2 + bb2);
      float oB = sigf(z3.y + pB3 + bb3);
      float rB = sigf(z4.y + pB4 + bb4);
      float cnB = iB * gB + fB * cB; cB = cnB;
      float hB = rB * (oB * tanhf_(cnB)) + (1.f - rB) * pB6;

      unsigned short hbA = f2bf(hA), hbB = f2bf(hB);
      ull word = ((ull)(unsigned)(tagbase + s + 1) << 32)
               | ((unsigned)hbA << 16) | (unsigned)hbB;
      int pidx = ((s + 1) & 1) * 600 + rp * 300 + j2;
      st64_plain(hwf + pidx, word);   // fast: local-L2 visible
      st64_sys(hws + pidx, word);     // slow: MALL visible (always correct)
      int lrA = len_s[2 * rp], lrB = len_s[2 * rp + 1];
      if (s < lrA) {
        int t = rev ? (lrA - 1 - s) : s;
        int br = brbase + 2 * rp;
        hid[((size_t)t * B_ + br) * H_ + j2] = hA;
        xb[((size_t)t * B_ + br) * H_ + j2] = hbA;
      }
      if (s < lrB) {
        int t = rev ? (lrB - 1 - s) : s;
        int br = brbase + 2 * rp + 1;
        hid[((size_t)t * B_ + br) * H_ + j2] = hB;
        xb[((size_t)t * B_ + br) * H_ + j2] = hbB;
      }
    }
    // no trailing barrier needed: next stash can only start after our own gates
    // publish (we poll our own words too); h_lds/z_lds hazards separated by the
    // two barriers above.
  }
}

extern "C" void kernel_launch(void* const* d_in, const int* in_sizes, int n_in,
                              void* d_out, int out_size, void* d_ws, size_t ws_size,
                              hipStream_t stream) {
  const float* inputs = (const float*)d_in[0];
  const int* lengths = (const int*)d_in[1];
  const float* W_ih0 = (const float*)d_in[2];
  const float* W_ih_rest = (const float*)d_in[3];
  const float* W_hh = (const float*)d_in[4];
  const float* b_hh = (const float*)d_in[5];
  float* outp = (float*)d_out;
  float* hidden = outp + (size_t)B_ * T_ * H_;   // [L][T,B,H]

  char* ws = (char*)d_ws;
  float* pi = (float*)ws;                                         // M_*NG fp32 (118MB)
  size_t off = (size_t)M_ * NG * 4;
  unsigned short* xb = (unsigned short*)(ws + off);               // M_*H_ bf16
  off += (size_t)M_ * H_ * 2;
  unsigned short* Wb = (unsigned short*)(ws + off);               // 4,140,000 bf16
  off += 4140000ull * 2;
  ull* h_words = (ull*)(ws + off);   // fast[16][1200] + slow[16][1200] u64
  size_t hw_bytes = 32ull * 1200 * 8;
  off += hw_bytes;

  hipMemsetAsync(d_out, 0, (size_t)out_size * 4, stream);         // zero padding regions
  hipMemsetAsync(h_words, 0, hw_bytes, stream);                   // clear tags

  {
    int n = D_ * NG + (L_ - 1) * H_ * NG;
    k_convert_w<<<(n + 255) / 256, 256, 0, stream>>>(W_ih0, W_ih_rest, Wb);
  }
  {
    int n = T_ * B_ * D_;
    k_transpose_in<<<(n + 255) / 256, 256, 0, stream>>>(inputs, xb);
  }
  for (int l = 0; l < L_; l++) {
    const unsigned short* Wihb = (l == 0) ? Wb : (Wb + 360000 + (size_t)(l - 1) * 540000);
    int K = (l == 0) ? D_ : H_;
    k_gemm<<<dim3(M_ / 64, (NG + 63) / 64), 256, 0, stream>>>(xb, Wihb, pi, K);
    float* hid_l = hidden + (size_t)l * T_ * B_ * H_;
    k_recur<<<192, 512, 0, stream>>>(pi, W_hh + (size_t)l * H_ * NZ, b_hh + (size_t)l * NZ,
                                     lengths, hid_l, xb, h_words, l & 1, l * 300);
  }
  k_out<<<((B_ * T_ * H_) + 255) / 256, 256, 0, stream>>>(
      hidden + (size_t)(L_ - 1) * T_ * B_ * H_, outp);
}

// Round 4
// 3473.460 us; speedup vs baseline: 1.6404x; 1.1912x over previous
//
#include <hip/hip_runtime.h>
#include <hip/hip_bf16.h>

#define B_ 64
#define T_ 256
#define D_ 200
#define H_ 300
#define L_ 8
#define M_ 16384      // T_*B_
#define NG 1800       // 6H
#define NZ 1500       // 5H
#define KP 320        // padded K stride for xb / WbT
#define NBP 1920      // padded N rows for WbT (15*128)

typedef __attribute__((ext_vector_type(8))) short bf16x8;
typedef __attribute__((ext_vector_type(4))) float f32x4;
typedef __attribute__((ext_vector_type(4))) unsigned u32x4;
typedef unsigned long long ull;

__device__ __forceinline__ unsigned short f2bf(float f) {
  union { float f; unsigned u; } v; v.f = f;
  unsigned r = v.u + 0x7fffu + ((v.u >> 16) & 1u);   // RNE
  return (unsigned short)(r >> 16);
}

__device__ __forceinline__ float sigf(float x) { return 1.f / (1.f + __expf(-x)); }
__device__ __forceinline__ float tanhf_(float x) {
  x = fminf(15.f, fmaxf(-15.f, x));
  float e = __expf(2.f * x);
  return (e - 1.f) / (e + 1.f);
}

// raw barrier: LDS-only wait (no vmcnt drain -> global loads/stores stay in flight)
#define BARRIER() asm volatile("s_waitcnt lgkmcnt(0)\n\ts_barrier" ::: "memory")

// ---- exchange memory helpers ----
__device__ __forceinline__ u32x4 ld128_nt(const ull* p) {
  u32x4 v;
  asm volatile("global_load_dwordx4 %0, %1, off nt\n\ts_waitcnt vmcnt(0)"
               : "=v"(v) : "v"(p) : "memory");
  return v;
}
__device__ __forceinline__ u32x4 ld128_sys(const ull* p) {
  u32x4 v;
  asm volatile("global_load_dwordx4 %0, %1, off sc0 sc1\n\ts_waitcnt vmcnt(0)"
               : "=v"(v) : "v"(p) : "memory");
  return v;
}
__device__ __forceinline__ void st64_plain(ull* p, ull v) {
  asm volatile("global_store_dwordx2 %0, %1, off" :: "v"(p), "v"(v) : "memory");
}
__device__ __forceinline__ void st64_sys(ull* p, ull v) {
  asm volatile("global_store_dwordx2 %0, %1, off sc0 sc1" :: "v"(p), "v"(v) : "memory");
}

// async global->LDS, 16B per lane; LDS dest = wave-uniform base + lane*16
__device__ __forceinline__ void gl_lds16(const unsigned short* g, unsigned short* l) {
  __builtin_amdgcn_global_load_lds(
      (const __attribute__((address_space(1))) void*)g,
      (__attribute__((address_space(3))) void*)l, 16, 0, 0);
}

// ---- weight transpose+pad: W[k][n] fp32 -> WbT[l][n][k] bf16, [NBP][KP], zero-padded ----
__global__ void k_transpose_w(const float* __restrict__ W0, const float* __restrict__ Wr,
                              unsigned short* __restrict__ WbT) {
  __shared__ unsigned short t_lds[64][65];
  const int n0 = blockIdx.x * 64;
  const int k0 = blockIdx.y * 64;
  const int l = blockIdx.z;
  const int Kl = (l == 0) ? D_ : H_;
  const float* W = (l == 0) ? W0 : (Wr + (size_t)(l - 1) * H_ * NG);
  unsigned short* out = WbT + (size_t)l * NBP * KP;
  const int tx = threadIdx.x & 63;
  const int ty = threadIdx.x >> 6;     // 0..3
  #pragma unroll
  for (int i = 0; i < 16; i++) {
    int k = k0 + ty * 16 + i;
    int n = n0 + tx;
    float v = (k < Kl && n < NG) ? W[(size_t)k * NG + n] : 0.f;
    t_lds[ty * 16 + i][tx] = f2bf(v);
  }
  __syncthreads();
  #pragma unroll
  for (int i = 0; i < 16; i++) {
    int n = n0 + ty * 16 + i;
    if (n < NG) out[(size_t)n * KP + k0 + tx] = t_lds[tx][ty * 16 + i];
  }
}

// ---- inputs [B,T,D] fp32 -> time-major xb [T*B][KP] bf16 (pad cols zeroed by memset) ----
__global__ void k_transpose_in(const float* __restrict__ inp, unsigned short* __restrict__ xb) {
  int i = blockIdx.x * blockDim.x + threadIdx.x;     // over T_*B_*D_
  if (i >= T_ * B_ * D_) return;
  int d = i % D_;
  int r = i / D_;       // t*B_+b
  int b = r % B_;
  int t = r / B_;
  xb[(size_t)r * KP + d] = f2bf(inp[((size_t)b * T_ + t) * D_ + d]);
}

// ---- hidden[7] [T,B,H] -> output [B,T,H] ----
__global__ void k_out(const float* __restrict__ hid7, float* __restrict__ outp) {
  int i = blockIdx.x * blockDim.x + threadIdx.x;     // over B_*T_*H_
  if (i >= B_ * T_ * H_) return;
  int j = i % H_;
  int r = i / H_;
  int t = r % T_;
  int b = r / T_;
  outp[i] = hid7[((size_t)t * B_ + b) * H_ + j];
}

// ---- pi GEMM: C[M,1800] = A[M][KP] bf16 * BtT (N-major [NBP][KP]) bf16 ----
// 128x128 tile, 4 waves (2x2), K-step 32, global_load_lds width-16 staging.
// k-slot XOR swizzle (slot ^= row&3) applied at BOTH the pre-swizzled global
// source and the LDS reader -> ds_read_b128 conflicts reduced to free 2-way.
__global__ __launch_bounds__(256) void k_gemm(const unsigned short* __restrict__ A,
                                              const unsigned short* __restrict__ Bt,
                                              float* __restrict__ C, int nk) {
  __shared__ unsigned short As[128 * 32];
  __shared__ unsigned short Bs[128 * 32];
  const int bm = blockIdx.x, bn = blockIdx.y;
  const int tid = threadIdx.x;
  const int lane = tid & 63, wid = tid >> 6;
  const int wm = wid & 1, wn = wid >> 1;
  const int l16 = lane & 15, quad = lane >> 4;
  const int srow = lane >> 2;                          // row within 16-row chunk
  const int sswz = ((lane & 3) ^ (srow & 3)) << 3;     // staging source k-slot (shorts)
  const int sA = ((quad ^ (l16 & 3)) << 3);            // reader k-slot (shorts)
  const size_t arow0 = (size_t)bm * 128;
  const size_t brow0 = (size_t)bn * 128;
  f32x4 acc[4][4] = {};
  for (int kc = 0; kc < nk; kc++) {
    const int k0 = kc << 5;
    #pragma unroll
    for (int r = 0; r < 2; r++) {
      const int rbase = r * 64 + wid * 16;
      gl_lds16(A  + (arow0 + rbase + srow) * KP + k0 + sswz, &As[rbase * 32]);
      gl_lds16(Bt + (brow0 + rbase + srow) * KP + k0 + sswz, &Bs[rbase * 32]);
    }
    asm volatile("s_waitcnt vmcnt(0)" ::: "memory");
    __syncthreads();
    bf16x8 af[4], bfr[4];
    #pragma unroll
    for (int i = 0; i < 4; i++) {
      af[i]  = *(const bf16x8*)&As[(wm * 64 + i * 16 + l16) * 32 + sA];
      bfr[i] = *(const bf16x8*)&Bs[(wn * 64 + i * 16 + l16) * 32 + sA];
    }
    #pragma unroll
    for (int mi = 0; mi < 4; mi++)
      #pragma unroll
      for (int ni = 0; ni < 4; ni++)
        acc[mi][ni] = __builtin_amdgcn_mfma_f32_16x16x32_bf16(af[mi], bfr[ni], acc[mi][ni], 0, 0, 0);
    __syncthreads();
  }
  const int row0 = bm * 128 + wm * 64 + quad * 4;
  const int col0 = bn * 128 + wn * 64 + l16;
  #pragma unroll
  for (int mi = 0; mi < 4; mi++) {
    #pragma unroll
    for (int ni = 0; ni < 4; ni++) {
      int col = col0 + ni * 16;
      if (col < NG) {
        #pragma unroll
        for (int i = 0; i < 4; i++)
          C[(size_t)(row0 + mi * 16 + i) * NG + col] = acc[mi][ni][i];
      }
    }
  }
}

// ---- persistent recurrence: 192 blocks = 16 batch-groups (4 rows) x 12 column-blocks ----
// R8: raw barriers (lgkmcnt-only) so gate-wave global loads/stores never drain at
// the rendezvous; pi prefetch software-pipelined one step ahead in registers.
// Exchange: dual-publish (plain->local L2 fast area, sc0sc1->MALL slow area) +
// nt-poll with sys probe every 32 misses (self-healing, liveness unconditional).
__global__ __launch_bounds__(512, 2) void k_recur(
    const float* __restrict__ pi, const float* __restrict__ Whh,
    const float* __restrict__ bias, const int* __restrict__ lens,
    float* __restrict__ hid, unsigned short* __restrict__ xb,
    ull* __restrict__ h_words, int rev, int tagbase)
{
  __shared__ __align__(16) unsigned short h_lds[16 * 328]; // bf16 [row][k], rows 4-15 & k>=300 zero
  __shared__ __align__(16) float z_lds[128 * 4];           // [n][r]
  __shared__ float bias_s[128];
  __shared__ int len_s[4];

  const int tid = threadIdx.x;
  const int bid = blockIdx.x;
  const int g = bid & 15;    // batch group
  const int cb = bid >> 4;   // column block 0..11

  const int lane = tid & 63;
  const int wid = tid >> 6;          // 0..7 = N-tile index
  const int l16 = lane & 15;
  const int quad = lane >> 4;

  const int rp = tid / 25;           // gate mapping (tid<50): row-pair 0..1
  const int gj = tid - rp * 25;      // j within 25
  const int j2 = cb * 25 + gj;

  // ---- preload Whh B-fragments: wfrag[c], n = wid*16+l16, k = c*32+quad*8+j ----
  bf16x8 wfrag[10];
  {
    int n = wid * 16 + l16;
    bool vn = n < 125;
    int colw = vn ? ((n / 25) * 300 + cb * 25 + (n % 25)) : 0;
    #pragma unroll
    for (int c = 0; c < 10; c++) {
      bf16x8 f;
      #pragma unroll
      for (int j = 0; j < 8; j++) {
        int k = c * 32 + quad * 8 + j;
        float v = (vn && k < 300) ? Whh[(size_t)k * NZ + colw] : 0.f;
        f[j] = (short)f2bf(v);
      }
      wfrag[c] = f;
    }
  }
  if (tid < 4) len_s[tid] = lens[g * 4 + tid];
  if (tid < 125) bias_s[tid] = bias[(tid / 25) * 300 + cb * 25 + (tid % 25)];
  for (int i = tid; i < 16 * 328; i += 512) h_lds[i] = 0;  // zero pad rows/cols
  __syncthreads();

  int S = len_s[0];
  S = len_s[1] > S ? len_s[1] : S;
  S = len_s[2] > S ? len_s[2] : S;
  S = len_s[3] > S ? len_s[3] : S;

  ull* hwf = h_words + (size_t)g * 1200;                   // fast area [parity][600]
  ull* hws = h_words + 16 * 1200 + (size_t)g * 1200;       // slow area [parity][600]
  const int brbase = g * 4;
  float cA = 0.f, cB = 0.f;          // cell state, rows 2rp / 2rp+1 (tid<50)

  // pipelined pi prefetch (gate threads): values for step ss loaded one step early
  float pA0 = 0.f, pA1 = 0.f, pA2 = 0.f, pA3 = 0.f, pA4 = 0.f, pA6 = 0.f;
  float pB0 = 0.f, pB1 = 0.f, pB2 = 0.f, pB3 = 0.f, pB4 = 0.f, pB6 = 0.f;
#define PI_PREF(ss) do {                                                          \
    int lrA_ = len_s[2 * rp], lrB_ = len_s[2 * rp + 1];                           \
    pA0 = pA1 = pA2 = pA3 = pA4 = pA6 = 0.f;                                      \
    pB0 = pB1 = pB2 = pB3 = pB4 = pB6 = 0.f;                                      \
    if ((ss) < lrA_) {                                                            \
      int t_ = rev ? (lrA_ - 1 - (ss)) : (ss);                                    \
      const float* pr_ = pi + ((size_t)t_ * B_ + (brbase + 2 * rp)) * NG;         \
      pA0 = pr_[j2]; pA1 = pr_[300 + j2]; pA2 = pr_[600 + j2];                    \
      pA3 = pr_[900 + j2]; pA4 = pr_[1200 + j2]; pA6 = pr_[NZ + j2];              \
    }                                                                             \
    if ((ss) < lrB_) {                                                            \
      int t_ = rev ? (lrB_ - 1 - (ss)) : (ss);                                    \
      const float* pr_ = pi + ((size_t)t_ * B_ + (brbase + 2 * rp + 1)) * NG;     \
      pB0 = pr_[j2]; pB1 = pr_[300 + j2]; pB2 = pr_[600 + j2];                    \
      pB3 = pr_[900 + j2]; pB4 = pr_[1200 + j2]; pB6 = pr_[NZ + j2];              \
    }                                                                             \
  } while (0)
  if (tid < 50) PI_PREF(0);

  for (int s = 0; s < S; s++) {
    if (s > 0 && tid >= 64 && tid < 364) {
      const unsigned tg = (unsigned)(tagbase + s);          // tag of h_s
      const size_t par = (size_t)(s & 1) * 600;
      const int pt = tid - 64;                              // 0..299
      const ull* pf = hwf + par + 2 * pt;
      const ull* ps = hws + par + 2 * pt;
      u32x4 v;
      int miss = 0;
      for (;;) {
        v = ld128_nt(pf);                                   // local-L2 fast probe
        if ((v.y == tg) && (v.w == tg)) break;
        if ((++miss & 31) == 0) {
          v = ld128_sys(ps);                                // MALL truth probe
          if ((v.y == tg) && (v.w == tg)) break;
          __builtin_amdgcn_s_sleep(1);
        }
      }
      // stash bf16 payloads into LDS A-operand layout (2 rows per u64 word)
      int w0 = pt << 1;
      int r2 = (w0 >= 300) ? 1 : 0;
      int k = w0 - r2 * 300;
      h_lds[(2 * r2) * 328 + k]     = (unsigned short)(v.x >> 16);
      h_lds[(2 * r2 + 1) * 328 + k] = (unsigned short)(v.x & 0xffffu);
      int w1 = w0 + 1;
      int r2b = (w1 >= 300) ? 1 : 0;
      int kb = w1 - r2b * 300;
      h_lds[(2 * r2b) * 328 + kb]     = (unsigned short)(v.z >> 16);
      h_lds[(2 * r2b + 1) * 328 + kb] = (unsigned short)(v.z & 0xffffu);
    }
    BARRIER();

    f32x4 acc = {0, 0, 0, 0};
    if (s > 0) {
      f32x4 acc2 = {0, 0, 0, 0};
      const unsigned short* abase = &h_lds[l16 * 328 + quad * 8];
      #pragma unroll
      for (int c = 0; c < 10; c += 2) {
        bf16x8 a0 = *(const bf16x8*)(abase + c * 32);
        bf16x8 a1 = *(const bf16x8*)(abase + c * 32 + 32);
        acc  = __builtin_amdgcn_mfma_f32_16x16x32_bf16(a0, wfrag[c],     acc,  0, 0, 0);
        acc2 = __builtin_amdgcn_mfma_f32_16x16x32_bf16(a1, wfrag[c + 1], acc2, 0, 0, 0);
      }
      acc += acc2;
    }
    // C layout: col=lane&15, row=quad*4+reg -> lanes 0-15 hold rows 0-3 in regs 0-3
    if (quad == 0) {
      int n = wid * 16 + l16;
      *(f32x4*)&z_lds[n * 4] = acc;
    }
    BARRIER();

    if (tid < 50) {
      const float bb0 = bias_s[gj],      bb1 = bias_s[25 + gj], bb2 = bias_s[50 + gj];
      const float bb3 = bias_s[75 + gj], bb4 = bias_s[100 + gj];
      const float2 z0 = *(const float2*)&z_lds[(gj      ) * 4 + 2 * rp];
      const float2 z1 = *(const float2*)&z_lds[(25 + gj ) * 4 + 2 * rp];
      const float2 z2 = *(const float2*)&z_lds[(50 + gj ) * 4 + 2 * rp];
      const float2 z3 = *(const float2*)&z_lds[(75 + gj ) * 4 + 2 * rp];
      const float2 z4 = *(const float2*)&z_lds[(100 + gj) * 4 + 2 * rp];
      // row A = 2rp
      float iA = sigf(z0.x + pA0 + bb0);
      float fA = sigf(z1.x + pA1 + bb1);
      float gA = tanhf_(z2.x + pA2 + bb2);
      float oA = sigf(z3.x + pA3 + bb3);
      float rA = sigf(z4.x + pA4 + bb4);
      float cnA = iA * gA + fA * cA; cA = cnA;
      float hA = rA * (oA * tanhf_(cnA)) + (1.f - rA) * pA6;
      // row B = 2rp+1
      float iB = sigf(z0.y + pB0 + bb0);
      float fB = sigf(z1.y + pB1 + bb1);
      float gB = tanhf_(z2.y + pB2 + bb2);
      float oB = sigf(z3.y + pB3 + bb3);
      float rB = sigf(z4.y + pB4 + bb4);
      float cnB = iB * gB + fB * cB; cB = cnB;
      float hB = rB * (oB * tanhf_(cnB)) + (1.f - rB) * pB6;

      unsigned short hbA = f2bf(hA), hbB = f2bf(hB);
      ull word = ((ull)(unsigned)(tagbase + s + 1) << 32)
               | ((unsigned)hbA << 16) | (unsigned)hbB;
      int pidx = ((s + 1) & 1) * 600 + rp * 300 + j2;
      st64_plain(hwf + pidx, word);   // fast: local-L2 visible
      st64_sys(hws + pidx, word);     // slow: MALL visible (always correct)
      int lrA = len_s[2 * rp], lrB = len_s[2 * rp + 1];
      if (s < lrA) {
        int t = rev ? (lrA - 1 - s) : s;
        int br = brbase + 2 * rp;
        hid[((size_t)t * B_ + br) * H_ + j2] = hA;
        xb[((size_t)t * B_ + br) * KP + j2] = hbA;
      }
      if (s < lrB) {
        int t = rev ? (lrB - 1 - s) : s;
        int br = brbase + 2 * rp + 1;
        hid[((size_t)t * B_ + br) * H_ + j2] = hB;
        xb[((size_t)t * B_ + br) * KP + j2] = hbB;
      }
      PI_PREF(s + 1);                 // in flight across next step's barriers
    }
  }
#undef PI_PREF
}

extern "C" void kernel_launch(void* const* d_in, const int* in_sizes, int n_in,
                              void* d_out, int out_size, void* d_ws, size_t ws_size,
                              hipStream_t stream) {
  const float* inputs = (const float*)d_in[0];
  const int* lengths = (const int*)d_in[1];
  const float* W_ih0 = (const float*)d_in[2];
  const float* W_ih_rest = (const float*)d_in[3];
  const float* W_hh = (const float*)d_in[4];
  const float* b_hh = (const float*)d_in[5];
  float* outp = (float*)d_out;
  float* hidden = outp + (size_t)B_ * T_ * H_;   // [L][T,B,H]

  char* ws = (char*)d_ws;
  float* pi = (float*)ws;                                         // M_*NG fp32 (118MB)
  size_t off = (size_t)M_ * NG * 4;
  unsigned short* xb = (unsigned short*)(ws + off);               // M_*KP bf16 (10.5MB)
  off += (size_t)M_ * KP * 2;
  unsigned short* WbT = (unsigned short*)(ws + off);              // 8*NBP*KP bf16 (9.8MB)
  off += (size_t)L_ * NBP * KP * 2;
  ull* h_words = (ull*)(ws + off);   // fast[16][1200] + slow[16][1200] u64
  size_t hw_bytes = 32ull * 1200 * 8;
  off += hw_bytes;

  hipMemsetAsync(d_out, 0, (size_t)out_size * 4, stream);         // zero padding regions
  hipMemsetAsync(h_words, 0, hw_bytes, stream);                   // clear tags
  hipMemsetAsync(xb, 0, (size_t)M_ * KP * 2, stream);             // zero K padding
  hipMemsetAsync(WbT, 0, (size_t)L_ * NBP * KP * 2, stream);      // zero N/K padding

  k_transpose_w<<<dim3(29, 5, 8), 256, 0, stream>>>(W_ih0, W_ih_rest, WbT);
  {
    int n = T_ * B_ * D_;
    k_transpose_in<<<(n + 255) / 256, 256, 0, stream>>>(inputs, xb);
  }
  for (int l = 0; l < L_; l++) {
    const unsigned short* Bt = WbT + (size_t)l * NBP * KP;
    int nk = (l == 0) ? 7 : 10;      // ceil(K/32): 200->7 (pad zero), 300->10
    k_gemm<<<dim3(M_ / 128, NBP / 128), 256, 0, stream>>>(xb, Bt, pi, nk);
    float* hid_l = hidden + (size_t)l * T_ * B_ * H_;
    k_recur<<<192, 512, 0, stream>>>(pi, W_hh + (size_t)l * H_ * NZ, b_hh + (size_t)l * NZ,
                                     lengths, hid_l, xb, h_words, l & 1, l * 300);
  }
  k_out<<<((B_ * T_ * H_) + 255) / 256, 256, 0, stream>>>(
      hidden + (size_t)(L_ - 1) * T_ * B_ * H_, outp);
}